// Round 1
// baseline (9732.102 us; speedup 1.0000x reference)
//
#include <hip/hip_runtime.h>
#include <stdint.h>
#include <math.h>

// ---------------------------------------------------------------------------
// NMT seq2seq: encoder LSTM (S=1024) -> decoder LSTM + local attention (T=64)
// -> fused projection/log-softmax NLL.
//
// Round 5: single-hop packed-tag barrier.  The old hierarchical barrier cost
// two MALL round trips per step (worker flag -> master poll -> epoch ->
// worker poll) plus master serialization and sleep quantization.  Now the
// activation wave (tid<64, the sole producer of h) drains its own stores
// with an in-wave vmcnt(0), lane `wg` publishes a monotone step tag (16B
// stride; 64 tags = 8 cache lines/chain), and all 64 lanes poll all 64 tags
// with ONE coalesced bypass load per iteration.  One hop, no master, one
// fewer __syncthreads per step.  All cross-WG data stays at monotonically
// fresh addresses (cold in consumer caches), so plain cached consumer loads
// remain correct; only tags are re-read and those use bypass loads.
// ---------------------------------------------------------------------------

typedef _Float16 f16;
typedef _Float16 f16x2 __attribute__((ext_vector_type(2)));

union V8 { f16x2 p[4]; float4 f4; };

#define CH  4            // independent batch chains
#define WPC 64           // workgroups per chain
#define FLAG_STRIDE 32   // ints; allocation stride kept from round 4
#define TAG_STRIDE 4     // ints; 16B per tag -> 64 tags span 8 cache lines

__device__ __forceinline__ float dot2f(f16x2 a, f16x2 b, float c) {
#if __has_builtin(__builtin_amdgcn_fdot2)
    return __builtin_amdgcn_fdot2(a, b, c, false);
#else
    return c + (float)a[0] * (float)b[0] + (float)a[1] * (float)b[1];
#endif
}

__device__ __forceinline__ float sigf(float x) { return 1.0f / (1.0f + __expf(-x)); }

__device__ __forceinline__ float tanh_f(float x) {
    float ax = fminf(fabsf(x), 12.0f);
    float e  = __expf(2.0f * ax);
    float r  = (e - 1.0f) / (e + 1.0f);
    return copysignf(r, x);
}

// write-through stores: bypass L1/L2, land at coherence point (MALL)
__device__ __forceinline__ void st_wt_b16(f16* p, f16 v) {
    union { f16 h; uint16_t u; } cv; cv.h = v;
    uint32_t d = cv.u;
    asm volatile("global_store_short %0, %1, off sc0 sc1" :: "v"(p), "v"(d) : "memory");
}
__device__ __forceinline__ void st_wt_b32(int* p, int v) {
    asm volatile("global_store_dword %0, %1, off sc0 sc1" :: "v"(p), "v"(v) : "memory");
}
__device__ __forceinline__ void st_wt_f32(float* p, float v) {
    union { float f; int i; } cv; cv.f = v;
    asm volatile("global_store_dword %0, %1, off sc0 sc1" :: "v"(p), "v"(cv.i) : "memory");
}
__device__ __forceinline__ int ld_bypass(const int* p) {
    int v;
    asm volatile("global_load_dword %0, %1, off sc0 sc1\n\ts_waitcnt vmcnt(0)"
                 : "=v"(v) : "v"(p) : "memory");
    return v;
}

// Single-hop tag barrier among the WPC co-resident WGs of one chain.
// Lane `wg` publishes this WG's tag; all 64 lanes poll all 64 tags with one
// coalesced bypass load per spin iteration (the load RT self-throttles).
// PRECONDITION: the calling WG's producing stores are drained before entry:
//   - wave-0 producers: s_waitcnt vmcnt(0) inside the tid<64 branch
//   - all-wave producers: s_waitcnt vmcnt(0) + __syncthreads() first
__device__ __forceinline__ void gbar1(int* tags, int wg, int step) {
    const int tid = threadIdx.x;
    if (tid < 64) {
        if (tid == wg) st_wt_b32(tags + wg * TAG_STRIDE, step);
        const int* tp = tags + tid * TAG_STRIDE;
        while (ld_bypass(tp) < step) {}
    }
    __syncthreads();
}

// gate-column permutation: global permuted col n (0..2047) -> original (4H) row.
// n = wg*32 + g*8 + uu  ->  g*512 + wg*8 + uu   (WG wg owns h-units wg*8..wg*8+8)
__device__ __forceinline__ int rowp(int n) {
    return (((n & 31) >> 3) * 512) + ((n >> 5) * 8) + (n & 7);
}

// ---------------------------------------------------------------------------
__global__ void zero_init(f16* h_hist, f16* q_hist, int* flags,
                          float* se, float* tl) {
    int i = blockIdx.x * blockDim.x + threadIdx.x;   // 16384 threads
    if (i < 16384) {
        int chain = i >> 12, off = i & 4095;
        h_hist[(size_t)chain * 1089 * 4096 + off] = (f16)0.0f;
        q_hist[(size_t)chain * 65 * 4096 + off]   = (f16)0.0f;
    }
    if (i < CH * WPC * FLAG_STRIDE) flags[i] = 0;
    if (i < 2048) { se[i] = 0.0f; tl[i] = 0.0f; }
}

// Convert / permute weights to f16 scan layouts.
__global__ void convert_weights(const float* __restrict__ encWhh,
                                const float* __restrict__ decWih,
                                const float* __restrict__ decWhh,
                                const float* __restrict__ ht2tan,
                                const float* __restrict__ ct2ht,
                                f16* __restrict__ Wenc, f16* __restrict__ Wdih,
                                f16* __restrict__ Wdhh, f16* __restrict__ T2l,
                                f16* __restrict__ CT2l) {
    const int NW = 2048 * 512;
    const int total = 3 * NW + 512 * 512 + 512 * 1024;
    int i = blockIdx.x * blockDim.x + threadIdx.x;
    int st = gridDim.x * blockDim.x;
    for (; i < total; i += st) {
        if (i < NW) {
            int n = i >> 9, k = i & 511;
            Wenc[i] = (f16)encWhh[rowp(n) * 512 + k];
        } else if (i < 2 * NW) {
            int j = i - NW; int n = j >> 9, k = j & 511;
            Wdih[j] = (f16)decWih[rowp(n) * 1024 + 512 + k];   // ht part of concat
        } else if (i < 3 * NW) {
            int j = i - 2 * NW; int n = j >> 9, k = j & 511;
            Wdhh[j] = (f16)decWhh[rowp(n) * 512 + k];
        } else if (i < 3 * NW + 512 * 512) {
            int j = i - 3 * NW;
            T2l[j] = (f16)ht2tan[j];
        } else {
            int j = i - 3 * NW - 512 * 512;
            CT2l[j] = (f16)ct2ht[j];
        }
    }
}

// 64x64-tile f32 GEMM, gathered A rows, bias, scan-layout output:
// value for (row r = t*32+B, permuted col n) stored at
// [t][chain=B>>3][wg=n>>5][c=n&31][bb=B&7].
template <typename OutT>
__global__ __launch_bounds__(256) void gemm_gather(
    const float* __restrict__ emb, const int* __restrict__ idx,
    const float* __restrict__ W, int ldw,
    const float* __restrict__ bias, OutT* __restrict__ out) {
    __shared__ float As[16][65];
    __shared__ float Bs[16][65];
    const int tid = threadIdx.x;
    const int n0 = blockIdx.x * 64;
    const int r0 = blockIdx.y * 64;
    const int tx = tid & 15, ty = tid >> 4;
    const int lk = tid & 3,  lr = tid >> 2;
    const float* arow = emb + (size_t)idx[r0 + lr] * 512 + lk * 4;
    const float* brow = W + (size_t)rowp(n0 + lr) * ldw + lk * 4;
    float acc[4][4] = {};
    for (int k0 = 0; k0 < 512; k0 += 16) {
        float4 av = *(const float4*)(arow + k0);
        float4 bv = *(const float4*)(brow + k0);
        __syncthreads();
        As[lk * 4 + 0][lr] = av.x; As[lk * 4 + 1][lr] = av.y;
        As[lk * 4 + 2][lr] = av.z; As[lk * 4 + 3][lr] = av.w;
        Bs[lk * 4 + 0][lr] = bv.x; Bs[lk * 4 + 1][lr] = bv.y;
        Bs[lk * 4 + 2][lr] = bv.z; Bs[lk * 4 + 3][lr] = bv.w;
        __syncthreads();
#pragma unroll
        for (int k = 0; k < 16; k++) {
            float a4[4], b4[4];
#pragma unroll
            for (int i = 0; i < 4; i++) a4[i] = As[k][ty * 4 + i];
#pragma unroll
            for (int j = 0; j < 4; j++) b4[j] = Bs[k][tx * 4 + j];
#pragma unroll
            for (int i = 0; i < 4; i++)
#pragma unroll
                for (int j = 0; j < 4; j++) acc[i][j] = fmaf(a4[i], b4[j], acc[i][j]);
        }
    }
#pragma unroll
    for (int j = 0; j < 4; j++) {
        int n = n0 + tx * 4 + j;
        float bv2 = bias[rowp(n)];
#pragma unroll
        for (int i = 0; i < 4; i++) {
            int r = r0 + ty * 4 + i;
            int t = r >> 5, B = r & 31;
            size_t addr = ((((size_t)t * 4 + (B >> 3)) * 64 + (n >> 5)) * 32
                           + (n & 31)) * 8 + (B & 7);
            out[addr] = (OutT)(acc[i][j] + bv2);
        }
    }
}

// ---------------------------------------------------------------------------
// Persistent scan: 256 WGs x 512 threads = 4 chains x 64 WGs.
// WG (chain, wg) owns 32 permuted gate cols (8 h-units x 4 gates) for the
// chain's 8 batches.
// ---------------------------------------------------------------------------
__global__ __launch_bounds__(512) void scan_kernel(
    const f16* __restrict__ eg,      // [1024][CH][64][32][8]
    const float* __restrict__ dg,    // [64][CH][64][32][8]
    const f16* __restrict__ Wenc,    // [2048][512] rows in permuted col order
    const f16* __restrict__ Wdih,    // [2048][512]
    const f16* __restrict__ Wdhh,    // [2048][512]
    const f16* __restrict__ T2l,     // [512][512]
    const f16* __restrict__ CT2l,    // [512][1024]
    const float* __restrict__ wpt,   // [512]
    f16* __restrict__ h_hist,        // [CH][1089][8][512] slot0 zeroed
    f16* __restrict__ q_hist,        // [CH][65][8][512]  slot0 zeroed
    f16* __restrict__ ctb,           // [64][CH][8][512]
    float* __restrict__ ppart,       // [64][CH][8][64]
    float* __restrict__ dout,        // [2048][512]
    int* flags) {                    // [CH][...]; first 64*TAG_STRIDE = tags
    const int bid = blockIdx.x;
    const int chain = bid >> 6;
    const int wg = bid & 63;
    const int tid = threadIdx.x;
    int bar = 0;

    f16* hc = h_hist + (size_t)chain * 1089 * 4096;
    f16* qc = q_hist + (size_t)chain * 65 * 4096;
    int* flc = flags + chain * WPC * FLAG_STRIDE;

    __shared__ __align__(16) f16  Ws[32 * 520];    // 33280 B
    __shared__ __align__(16) f16  hst[8 * 520];    //  8320 B
    __shared__ float part[512];                    //  2048 B
    __shared__ float zbS[64];
    __shared__ float spart[64 * 9];
    __shared__ float scS[64];
    __shared__ float atwS[64];
    __shared__ float ptS[1];

    // stage encoder weight slice (32 rows x 512) into LDS, 520-f16 padded rows
    {
        int r = tid >> 4, seg = tid & 15;
        const float4* s4 = (const float4*)(Wenc + (size_t)(wg * 32 + r) * 512) + seg * 4;
        float4 a0 = s4[0], a1 = s4[1], a2 = s4[2], a3 = s4[3];
        float4* d4 = (float4*)(Ws + r * 520) + seg * 4;
        d4[0] = a0; d4[1] = a1; d4[2] = a2; d4[3] = a3;
    }
    __syncthreads();

    const int c  = (tid >> 3) & 31;   // gate col (local)
    const int bq = tid & 7;           // batch (local)
    const int kh = tid >> 8;          // k half
    const int sb = tid >> 6, sj = tid & 63;   // h staging
    const int au = tid & 7, ab = tid >> 3;    // activation: uu, bq (tid<64)
    float creg = 0.0f;                // cell state (tid<64)

    float egv = 0.0f;
    if (kh == 0)
        egv = (float)eg[(size_t)chain * 16384 + wg * 256 + c * 8 + bq];

    // ---------------- encoder: 1024 steps, 1 barrier each ----------------
    for (int t = 0; t < 1024; t++) {
        {   // stage h[t] (8KB) -> LDS
            const float4* s4 = (const float4*)(hc + (size_t)t * 4096 + sb * 512) + sj;
            float4 v = *s4;
            *((float4*)(hst + sb * 520) + sj) = v;
        }
        float egn = 0.0f;
        if (kh == 0 && t < 1023)   // prefetch next step's gate (in flight thru dot)
            egn = (float)eg[((size_t)(t + 1) * 4 + chain) * 16384 + wg * 256 + c * 8 + bq];
        __syncthreads();
        {   // dot: col c, batch bq, k-half kh
            const f16* Wr = Ws + c * 520 + kh * 256;
            const f16* hr = hst + bq * 520 + kh * 256;
            float a0 = (kh == 0) ? egv : 0.0f;
#pragma unroll 8
            for (int k = 0; k < 256; k += 8) {
                V8 wv, xv;
                wv.f4 = *(const float4*)(Wr + k);
                xv.f4 = *(const float4*)(hr + k);
#pragma unroll
                for (int q = 0; q < 4; q++) a0 = dot2f(wv.p[q], xv.p[q], a0);
            }
            part[tid] = a0;
        }
        egv = egn;
        __syncthreads();
        if (tid < 64) {
            float gi = part[(au)      * 8 + ab] + part[256 + (au)      * 8 + ab];
            float gf = part[(8 + au)  * 8 + ab] + part[256 + (8 + au)  * 8 + ab];
            float gg = part[(16 + au) * 8 + ab] + part[256 + (16 + au) * 8 + ab];
            float go = part[(24 + au) * 8 + ab] + part[256 + (24 + au) * 8 + ab];
            float cc = sigf(gf) * creg + sigf(gi) * tanh_f(gg);
            float hh = sigf(go) * tanh_f(cc);
            creg = cc;
            st_wt_b16(hc + (size_t)(t + 1) * 4096 + ab * 512 + wg * 8 + au, (f16)hh);
            asm volatile("s_waitcnt vmcnt(0)" ::: "memory");   // drain wave-0 stores
        }
        gbar1(flc, wg, ++bar);
    }

    // ---------------- decoder: 64 steps, 4 barriers each ----------------
    for (int t = 0; t < 64; t++) {
        const f16* qsrc = qc + (size_t)t * 4096;          // prev ht
        const f16* hsrc = hc + (size_t)(1024 + t) * 4096; // prev h
        f16* ydst = hc + (size_t)(1025 + t) * 4096;       // yt

        // ---- stage A: gates = dg + Wih_h.ht + Whh.h (weights from L2) ----
        {
            float dgv = (kh == 0)
                ? dg[((size_t)t * 4 + chain) * 16384 + wg * 256 + c * 8 + bq] : 0.0f;
            const f16* W1 = Wdih + (size_t)(wg * 32 + c) * 512 + kh * 256;
            const f16* W2 = Wdhh + (size_t)(wg * 32 + c) * 512 + kh * 256;
            const f16* q0 = qsrc + bq * 512 + kh * 256;
            const f16* h0 = hsrc + bq * 512 + kh * 256;
            float a0 = dgv;
#pragma unroll 4
            for (int k = 0; k < 256; k += 8) {
                V8 w1, w2, x0, y0;
                w1.f4 = *(const float4*)(W1 + k);
                x0.f4 = *(const float4*)(q0 + k);
                w2.f4 = *(const float4*)(W2 + k);
                y0.f4 = *(const float4*)(h0 + k);
#pragma unroll
                for (int q = 0; q < 4; q++) {
                    a0 = dot2f(w1.p[q], x0.p[q], a0);
                    a0 = dot2f(w2.p[q], y0.p[q], a0);
                }
            }
            part[tid] = a0;
        }
        __syncthreads();
        if (tid < 64) {
            float gi = part[(au)      * 8 + ab] + part[256 + (au)      * 8 + ab];
            float gf = part[(8 + au)  * 8 + ab] + part[256 + (8 + au)  * 8 + ab];
            float gg = part[(16 + au) * 8 + ab] + part[256 + (16 + au) * 8 + ab];
            float go = part[(24 + au) * 8 + ab] + part[256 + (24 + au) * 8 + ab];
            float cc = sigf(gf) * creg + sigf(gi) * tanh_f(gg);
            float hh = sigf(go) * tanh_f(cc);
            creg = cc;
            st_wt_b16(ydst + ab * 512 + wg * 8 + au, (f16)hh);
            asm volatile("s_waitcnt vmcnt(0)" ::: "memory");
        }
        gbar1(flc, wg, ++bar);                // B1: yt visible

        // ---- stage B: z = tanh(yt @ W_ht2tan.T) units of this WG; pt partial ----
        {
            int kq = tid >> 6, zu = (tid >> 3) & 7, zq = tid & 7;
            const f16* Tr = T2l + (size_t)(wg * 8 + zu) * 512 + kq * 64;
            const f16* yr = ydst + zq * 512 + kq * 64;
            float s = 0.0f;
#pragma unroll
            for (int k = 0; k < 64; k += 8) {
                V8 aa, bb;
                aa.f4 = *(const float4*)(Tr + k);
                bb.f4 = *(const float4*)(yr + k);
#pragma unroll
                for (int q = 0; q < 4; q++) s = dot2f(aa.p[q], bb.p[q], s);
            }
            part[tid] = s;
        }
        __syncthreads();
        if (tid < 64) {
            float z = 0.0f;
#pragma unroll
            for (int kq = 0; kq < 8; kq++) z += part[kq * 64 + tid];
            zbS[tid] = tanh_f(z);             // zbS[zu*8 + zq]
        }
        __syncthreads();
        if (tid < 64) {
            if (tid < 8) {
                float pp = 0.0f;
#pragma unroll
                for (int u2 = 0; u2 < 8; u2++) pp += zbS[u2 * 8 + tid] * wpt[wg * 8 + u2];
                st_wt_f32(&ppart[(((size_t)t * 4 + chain) * 8 + tid) * 64 + wg], pp);
            }
            asm volatile("s_waitcnt vmcnt(0)" ::: "memory");
        }
        gbar1(flc, wg, ++bar);                // B2: pt partials visible

        // ---- stage C: local attention (WG wg<8 owns chain-batch wg) ----
        if (wg < 8) {
            const int bb = wg;
            if (tid < 64) {
                float v = ppart[(((size_t)t * 4 + chain) * 8 + bb) * 64 + tid];
#pragma unroll
                for (int off = 32; off > 0; off >>= 1) v += __shfl_down(v, off);
                if (tid == 0) ptS[0] = v;
            }
            __syncthreads();
            float pt = sigf(ptS[0]);
            float center = 1024.0f * pt;
            int ci = (int)floorf(center);
            int left = max(0, ci - 32);
            int right = min(1024, ci + 32);
            int win = right - left;
            int p = tid >> 3, seg = tid & 7;
            if (p < win) {
                const f16* yr = ydst + bb * 512 + seg * 64;
                const f16* er = hc + (size_t)(left + p + 1) * 4096 + bb * 512 + seg * 64;
                float s = 0.0f;
#pragma unroll
                for (int k = 0; k < 64; k += 8) {
                    V8 aa, bbv;
                    aa.f4  = *(const float4*)(yr + k);
                    bbv.f4 = *(const float4*)(er + k);
#pragma unroll
                    for (int q = 0; q < 4; q++) s = dot2f(aa.p[q], bbv.p[q], s);
                }
                spart[p * 9 + seg] = s;
            }
            __syncthreads();
            if (tid < 64) {
                float s = -1e30f;
                if (tid < win) {
                    s = 0.0f;
#pragma unroll
                    for (int x = 0; x < 8; x++) s += spart[tid * 9 + x];
                }
                scS[tid] = s;
            }
            __syncthreads();
            float mx = -1e30f;
            for (int q2 = 0; q2 < 64; q2++) mx = fmaxf(mx, scS[q2]);
            float sum = 0.0f;
            for (int q2 = 0; q2 < 64; q2++) sum += __expf(scS[q2] - mx);
            if (tid < 64) {
                float sp = (float)(left + tid) - center;
                float gs = __expf(-(sp * sp) * (1.0f / 512.0f));
                atwS[tid] = (tid < win) ? (__expf(scS[tid] - mx) / sum) * gs : 0.0f;
            }
            __syncthreads();
            {
                int j = tid;   // 0..511
                float a = 0.0f;
                const f16* ebase = hc + (size_t)(left + 1) * 4096 + bb * 512 + j;
                for (int p2 = 0; p2 < win; p2++)
                    a += atwS[p2] * (float)ebase[(size_t)p2 * 4096];
                st_wt_b16(ctb + ((((size_t)t * 4 + chain) * 8 + bb) * 512) + j, (f16)a);
            }
        }
        // all-wave producers: drain every wave, then barrier, then tag
        asm volatile("s_waitcnt vmcnt(0)" ::: "memory");
        __syncthreads();
        gbar1(flc, wg, ++bar);                // B3: ct visible

        // ---- stage D: ht_new = tanh([ct, yt] @ W_ct2ht.T) units of this WG ----
        {
            int kq = tid >> 6, du = (tid >> 3) & 7, dq = tid & 7;
            const f16* Cr = CT2l + (size_t)(wg * 8 + du) * 1024 + kq * 128;
            const f16* xr = (kq < 4)
                ? (ctb + ((((size_t)t * 4 + chain) * 8 + dq) * 512) + kq * 128)
                : (ydst + dq * 512 + (kq - 4) * 128);
            float s = 0.0f;
#pragma unroll 4
            for (int k = 0; k < 128; k += 8) {
                V8 aa, bb;
                aa.f4 = *(const float4*)(Cr + k);
                bb.f4 = *(const float4*)(xr + k);
#pragma unroll
                for (int q = 0; q < 4; q++) s = dot2f(aa.p[q], bb.p[q], s);
            }
            part[tid] = s;
        }
        __syncthreads();
        if (tid < 64) {
            float s = 0.0f;
#pragma unroll
            for (int kq = 0; kq < 8; kq++) s += part[kq * 64 + tid];
            float hv = tanh_f(s);
            int du = tid >> 3, dq = tid & 7;
            st_wt_b16(qc + (size_t)(t + 1) * 4096 + dq * 512 + wg * 8 + du, (f16)hv);
            dout[((size_t)t * 32 + chain * 8 + dq) * 512 + wg * 8 + du] = hv;
            asm volatile("s_waitcnt vmcnt(0)" ::: "memory");
        }
        gbar1(flc, wg, ++bar);                // B4: ht ready
    }
}

// ---------------------------------------------------------------------------
// Projection + fused exp-sum / target-logit extraction.
// ---------------------------------------------------------------------------
__global__ __launch_bounds__(256) void proj_lse(
    const float* __restrict__ A,      // dec_out [2048][512]
    const float* __restrict__ W,      // [32000][512]
    const int* __restrict__ target,   // [65][32]
    float* __restrict__ se, float* __restrict__ tl) {
    __shared__ float As[16][65];
    __shared__ float Bs[16][65];
    __shared__ float eb[64][17];
    const int tid = threadIdx.x;
    const int v0 = blockIdx.x * 64;
    const int r0 = blockIdx.y * 64;
    const int tx = tid & 15, ty = tid >> 4;
    const int lk = tid & 3,  lr = tid >> 2;
    const float* arow = A + (size_t)(r0 + lr) * 512 + lk * 4;
    const float* brow = W + (size_t)(v0 + lr) * 512 + lk * 4;
    float acc[4][4] = {};
    for (int k0 = 0; k0 < 512; k0 += 16) {
        float4 av = *(const float4*)(arow + k0);
        float4 bv = *(const float4*)(brow + k0);
        __syncthreads();
        As[lk * 4 + 0][lr] = av.x; As[lk * 4 + 1][lr] = av.y;
        As[lk * 4 + 2][lr] = av.z; As[lk * 4 + 3][lr] = av.w;
        Bs[lk * 4 + 0][lr] = bv.x; Bs[lk * 4 + 1][lr] = bv.y;
        Bs[lk * 4 + 2][lr] = bv.z; Bs[lk * 4 + 3][lr] = bv.w;
        __syncthreads();
#pragma unroll
        for (int k = 0; k < 16; k++) {
            float a4[4], b4[4];
#pragma unroll
            for (int i = 0; i < 4; i++) a4[i] = As[k][ty * 4 + i];
#pragma unroll
            for (int j = 0; j < 4; j++) b4[j] = Bs[k][tx * 4 + j];
#pragma unroll
            for (int i = 0; i < 4; i++)
#pragma unroll
                for (int j = 0; j < 4; j++) acc[i][j] = fmaf(a4[i], b4[j], acc[i][j]);
        }
    }
#pragma unroll
    for (int i = 0; i < 4; i++) {
        int rg = r0 + ty * 4 + i;
        int tg = target[32 + rg];
        float es = 0.0f;
#pragma unroll
        for (int j = 0; j < 4; j++) {
            int n = v0 + tx * 4 + j;
            float l = acc[i][j];
            if (n == tg) atomicAdd(&tl[rg], l);
            es += __expf(l);
        }
        eb[ty * 4 + i][tx] = es;
    }
    __syncthreads();
    if (tid < 64) {
        float s = 0.0f;
#pragma unroll
        for (int x = 0; x < 16; x++) s += eb[tid][x];
        atomicAdd(&se[r0 + tid], s);
    }
}

__global__ void finalize_out(const float* __restrict__ se, const float* __restrict__ tl,
                             const int* __restrict__ target, float* __restrict__ out) {
    int b = threadIdx.x;
    if (b >= 32) return;
    float s = 0.0f;
    for (int t = 0; t < 64; t++) {
        int r = t * 32 + b;
        int tg = target[(t + 1) * 32 + b];
        if (tg != 0) s += tl[r] - logf(se[r]);
    }
    out[b] = s;
}

// ---------------------------------------------------------------------------
extern "C" void kernel_launch(void* const* d_in, const int* in_sizes, int n_in,
                              void* d_out, int out_size, void* d_ws, size_t ws_size,
                              hipStream_t stream) {
    const int*   source   = (const int*)  d_in[0];
    const int*   target   = (const int*)  d_in[1];
    const float* src_emb  = (const float*)d_in[2];
    const float* tar_emb  = (const float*)d_in[3];
    const float* enc_Wih  = (const float*)d_in[4];
    const float* enc_Whh  = (const float*)d_in[5];
    const float* enc_b    = (const float*)d_in[6];
    const float* dec_Wih  = (const float*)d_in[7];
    const float* dec_Whh  = (const float*)d_in[8];
    const float* dec_b    = (const float*)d_in[9];
    const float* W_ht2tan = (const float*)d_in[10];
    const float* W_tan2pt = (const float*)d_in[11];
    const float* W_ct2ht  = (const float*)d_in[12];
    const float* W_final  = (const float*)d_in[13];
    float* out = (float*)d_out;

    char* ws = (char*)d_ws;
    size_t off = 0;
    auto alloc = [&](size_t bytes) -> char* {
        char* p = ws + off;
        off = (off + bytes + 255) & ~(size_t)255;
        return p;
    };
    f16*   h_hist = (f16*)  alloc((size_t)CH * 1089 * 4096 * 2);  // 35.7 MB
    f16*   q_hist = (f16*)  alloc((size_t)CH * 65 * 4096 * 2);
    f16*   ctb    = (f16*)  alloc((size_t)64 * CH * 8 * 512 * 2);
    float* ppart  = (float*)alloc((size_t)64 * CH * 8 * 64 * 4);
    float* se     = (float*)alloc((size_t)2048 * 4);
    float* tl     = (float*)alloc((size_t)2048 * 4);
    int*   flags  = (int*)  alloc((size_t)CH * WPC * FLAG_STRIDE * 4);
    f16*   eg     = (f16*)  alloc((size_t)32768 * 2048 * 2);      // 128 MB
    float* dg     = (float*)alloc((size_t)2048 * 2048 * 4);       // 16 MB
    f16*   Wenc   = (f16*)  alloc((size_t)2048 * 512 * 2);
    f16*   Wdih   = (f16*)  alloc((size_t)2048 * 512 * 2);
    f16*   Wdhh   = (f16*)  alloc((size_t)2048 * 512 * 2);
    f16*   T2l    = (f16*)  alloc((size_t)512 * 512 * 2);
    f16*   CT2l   = (f16*)  alloc((size_t)512 * 1024 * 2);
    float* dout   = (float*)alloc((size_t)2048 * 512 * 4);

    zero_init<<<64, 256, 0, stream>>>(h_hist, q_hist, flags, se, tl);
    convert_weights<<<2048, 256, 0, stream>>>(enc_Whh, dec_Wih, dec_Whh, W_ht2tan, W_ct2ht,
                                              Wenc, Wdih, Wdhh, T2l, CT2l);
    gemm_gather<f16><<<dim3(32, 512), 256, 0, stream>>>(src_emb, source, enc_Wih, 512,
                                                        enc_b, eg);
    gemm_gather<float><<<dim3(32, 32), 256, 0, stream>>>(tar_emb, target, dec_Wih, 1024,
                                                         dec_b, dg);
    scan_kernel<<<CH * WPC, 512, 0, stream>>>(eg, dg, Wenc, Wdih, Wdhh, T2l, CT2l,
                                              W_tan2pt, h_hist, q_hist, ctb, ppart,
                                              dout, flags);
    proj_lse<<<dim3(500, 32), 256, 0, stream>>>(dout, W_final, target, se, tl);
    finalize_out<<<1, 64, 0, stream>>>(se, tl, target, out);
}

// Round 3
// 8645.139 us; speedup vs baseline: 1.1257x; 1.1257x over previous
//
#include <hip/hip_runtime.h>
#include <stdint.h>
#include <math.h>

// ---------------------------------------------------------------------------
// NMT seq2seq: encoder LSTM (S=1024) -> decoder LSTM + local attention (T=64)
// -> fused projection/log-softmax NLL.
//
// Round 7: data-embedded sentinel synchronization (round-6 design) with the
// decoder staging coverage bug fixed: all staging polls now use 512 threads
// with b=tid>>6, j=tid&63 (64 x 16B chunks per 512-f16 row).  Round 6 used
// tid<256 / j=tid&31, which staged only HALF of each row -- decoder dots read
// uninitialized LDS (absmax 60).  Encoder staging was already correct.
//
// Sync design: all cross-WG payloads are write-once at monotonically fresh
// addresses; buffers are pre-filled with f16 0xFFFF / f32 0xFFFFFFFF (-NaN),
// unreachable by finite LSTM outputs.  Producers fire-and-forget st_wt
// (sc0 sc1 write-through to MALL); consumers spin on their own 16B chunk with
// bypass loads until NaN-free -- the poll IS the data load.  ~1.5-2 MALL RTs
// per handoff vs ~4.5 for the explicit-barrier chain.
// Safety: every writer of a polled buffer (incl. the fill) is write-through,
// so no dirty L2 line can shadow the MALL copy; polls bypass L1/L2; each 16B
// chunk has exactly one producer wave; per-step dep graph is acyclic.
// ---------------------------------------------------------------------------

typedef _Float16 f16;
typedef _Float16 f16x2 __attribute__((ext_vector_type(2)));
typedef int i32x4 __attribute__((ext_vector_type(4)));

union V8 { f16x2 p[4]; float4 f4; };

#define CH  4            // independent batch chains
#define WPC 64           // workgroups per chain

__device__ __forceinline__ float dot2f(f16x2 a, f16x2 b, float c) {
#if __has_builtin(__builtin_amdgcn_fdot2)
    return __builtin_amdgcn_fdot2(a, b, c, false);
#else
    return c + (float)a[0] * (float)b[0] + (float)a[1] * (float)b[1];
#endif
}

__device__ __forceinline__ float sigf(float x) { return 1.0f / (1.0f + __expf(-x)); }

__device__ __forceinline__ float tanh_f(float x) {
    float ax = fminf(fabsf(x), 12.0f);
    float e  = __expf(2.0f * ax);
    float r  = (e - 1.0f) / (e + 1.0f);
    return copysignf(r, x);
}

// write-through stores: bypass L1/L2, land at coherence point (MALL)
__device__ __forceinline__ void st_wt_b16(f16* p, f16 v) {
    union { f16 h; uint16_t u; } cv; cv.h = v;
    uint32_t d = cv.u;
    asm volatile("global_store_short %0, %1, off sc0 sc1" :: "v"(p), "v"(d) : "memory");
}
__device__ __forceinline__ void st_wt_f32(float* p, float v) {
    union { float f; int i; } cv; cv.f = v;
    asm volatile("global_store_dword %0, %1, off sc0 sc1" :: "v"(p), "v"(cv.i) : "memory");
}
__device__ __forceinline__ void st_wt_b128(i32x4* p, i32x4 v) {
    asm volatile("global_store_dwordx4 %0, %1, off sc0 sc1" :: "v"(p), "v"(v) : "memory");
}
// bypass loads: straight from MALL, never L1/L2 (so polling can't see stale)
__device__ __forceinline__ i32x4 ld_bypass4(const void* p) {
    i32x4 v;
    asm volatile("global_load_dwordx4 %0, %1, off sc0 sc1\n\ts_waitcnt vmcnt(0)"
                 : "=v"(v) : "v"(p) : "memory");
    return v;
}
__device__ __forceinline__ unsigned ld_bypass_u32(const void* p) {
    unsigned v;
    asm volatile("global_load_dword %0, %1, off sc0 sc1\n\ts_waitcnt vmcnt(0)"
                 : "=v"(v) : "v"(p) : "memory");
    return v;
}

// 16B chunk of 8 f16s is valid iff no half equals the sentinel 0xFFFF (-NaN).
// Real values are finite (|h|<1, |ct|<=64), so 0xFFFF is unreachable.
__device__ __forceinline__ bool chunk_ok(i32x4 v) {
    unsigned a = ~(unsigned)v[0], b = ~(unsigned)v[1];
    unsigned c = ~(unsigned)v[2], d = ~(unsigned)v[3];
    unsigned ok = (unsigned)((a & 0xFFFFu) != 0u) & (unsigned)((a >> 16) != 0u)
                & (unsigned)((b & 0xFFFFu) != 0u) & (unsigned)((b >> 16) != 0u)
                & (unsigned)((c & 0xFFFFu) != 0u) & (unsigned)((c >> 16) != 0u)
                & (unsigned)((d & 0xFFFFu) != 0u) & (unsigned)((d >> 16) != 0u);
    return ok != 0u;
}

__device__ __forceinline__ i32x4 poll16(const f16* gp) {
    i32x4 v = ld_bypass4(gp);
    while (!chunk_ok(v)) v = ld_bypass4(gp);
    return v;
}

// gate-column permutation: global permuted col n (0..2047) -> original (4H) row.
// n = wg*32 + g*8 + uu  ->  g*512 + wg*8 + uu   (WG wg owns h-units wg*8..wg*8+8)
__device__ __forceinline__ int rowp(int n) {
    return (((n & 31) >> 3) * 512) + ((n >> 5) * 8) + (n & 7);
}

// ---------------------------------------------------------------------------
// Sentinel fill (write-through!).  h_hist/q_hist slot 0 of each chain = 0.0
// (real initial state); everything else = 0xFFFF per f16 / 0xFFFFFFFF per f32.
// ---------------------------------------------------------------------------
__global__ void fill_sentinel(i32x4* h, i32x4* q, i32x4* c, i32x4* p,
                              float* se, float* tl) {
    const size_t NH = (size_t)CH * 1089 * 512;   // h_hist in int4 units
    const size_t NQ = (size_t)CH * 65 * 512;     // q_hist
    const size_t NC = (size_t)64 * CH * 8 * 64;  // ctb
    const size_t NP = (size_t)64 * CH * 8 * 16;  // ppart (f32)
    const size_t total = NH + NQ + NC + NP;
    const i32x4 S = {-1, -1, -1, -1};
    const i32x4 Z = {0, 0, 0, 0};
    size_t stp = (size_t)gridDim.x * blockDim.x;
    for (size_t i = (size_t)blockIdx.x * blockDim.x + threadIdx.x; i < total; i += stp) {
        if (i < NH) {
            size_t r = i % (size_t)(1089 * 512);
            st_wt_b128(h + i, (r < 512) ? Z : S);
        } else if (i < NH + NQ) {
            size_t j = i - NH;
            size_t r = j % (size_t)(65 * 512);
            st_wt_b128(q + j, (r < 512) ? Z : S);
        } else if (i < NH + NQ + NC) {
            st_wt_b128(c + (i - NH - NQ), S);
        } else {
            st_wt_b128(p + (i - NH - NQ - NC), S);
        }
    }
    size_t g = (size_t)blockIdx.x * blockDim.x + threadIdx.x;
    if (g < 2048) { se[g] = 0.0f; tl[g] = 0.0f; }
}

// Convert / permute weights to f16 scan layouts.
__global__ void convert_weights(const float* __restrict__ encWhh,
                                const float* __restrict__ decWih,
                                const float* __restrict__ decWhh,
                                const float* __restrict__ ht2tan,
                                const float* __restrict__ ct2ht,
                                f16* __restrict__ Wenc, f16* __restrict__ Wdih,
                                f16* __restrict__ Wdhh, f16* __restrict__ T2l,
                                f16* __restrict__ CT2l) {
    const int NW = 2048 * 512;
    const int total = 3 * NW + 512 * 512 + 512 * 1024;
    int i = blockIdx.x * blockDim.x + threadIdx.x;
    int st = gridDim.x * blockDim.x;
    for (; i < total; i += st) {
        if (i < NW) {
            int n = i >> 9, k = i & 511;
            Wenc[i] = (f16)encWhh[rowp(n) * 512 + k];
        } else if (i < 2 * NW) {
            int j = i - NW; int n = j >> 9, k = j & 511;
            Wdih[j] = (f16)decWih[rowp(n) * 1024 + 512 + k];   // ht part of concat
        } else if (i < 3 * NW) {
            int j = i - 2 * NW; int n = j >> 9, k = j & 511;
            Wdhh[j] = (f16)decWhh[rowp(n) * 512 + k];
        } else if (i < 3 * NW + 512 * 512) {
            int j = i - 3 * NW;
            T2l[j] = (f16)ht2tan[j];
        } else {
            int j = i - 3 * NW - 512 * 512;
            CT2l[j] = (f16)ct2ht[j];
        }
    }
}

// 64x64-tile f32 GEMM, gathered A rows, bias, scan-layout output:
// value for (row r = t*32+B, permuted col n) stored at
// [t][chain=B>>3][wg=n>>5][c=n&31][bb=B&7].
template <typename OutT>
__global__ __launch_bounds__(256) void gemm_gather(
    const float* __restrict__ emb, const int* __restrict__ idx,
    const float* __restrict__ W, int ldw,
    const float* __restrict__ bias, OutT* __restrict__ out) {
    __shared__ float As[16][65];
    __shared__ float Bs[16][65];
    const int tid = threadIdx.x;
    const int n0 = blockIdx.x * 64;
    const int r0 = blockIdx.y * 64;
    const int tx = tid & 15, ty = tid >> 4;
    const int lk = tid & 3,  lr = tid >> 2;
    const float* arow = emb + (size_t)idx[r0 + lr] * 512 + lk * 4;
    const float* brow = W + (size_t)rowp(n0 + lr) * ldw + lk * 4;
    float acc[4][4] = {};
    for (int k0 = 0; k0 < 512; k0 += 16) {
        float4 av = *(const float4*)(arow + k0);
        float4 bv = *(const float4*)(brow + k0);
        __syncthreads();
        As[lk * 4 + 0][lr] = av.x; As[lk * 4 + 1][lr] = av.y;
        As[lk * 4 + 2][lr] = av.z; As[lk * 4 + 3][lr] = av.w;
        Bs[lk * 4 + 0][lr] = bv.x; Bs[lk * 4 + 1][lr] = bv.y;
        Bs[lk * 4 + 2][lr] = bv.z; Bs[lk * 4 + 3][lr] = bv.w;
        __syncthreads();
#pragma unroll
        for (int k = 0; k < 16; k++) {
            float a4[4], b4[4];
#pragma unroll
            for (int i = 0; i < 4; i++) a4[i] = As[k][ty * 4 + i];
#pragma unroll
            for (int j = 0; j < 4; j++) b4[j] = Bs[k][tx * 4 + j];
#pragma unroll
            for (int i = 0; i < 4; i++)
#pragma unroll
                for (int j = 0; j < 4; j++) acc[i][j] = fmaf(a4[i], b4[j], acc[i][j]);
        }
    }
#pragma unroll
    for (int j = 0; j < 4; j++) {
        int n = n0 + tx * 4 + j;
        float bv2 = bias[rowp(n)];
#pragma unroll
        for (int i = 0; i < 4; i++) {
            int r = r0 + ty * 4 + i;
            int t = r >> 5, B = r & 31;
            size_t addr = ((((size_t)t * 4 + (B >> 3)) * 64 + (n >> 5)) * 32
                           + (n & 31)) * 8 + (B & 7);
            out[addr] = (OutT)(acc[i][j] + bv2);
        }
    }
}

// ---------------------------------------------------------------------------
// Persistent scan: 256 WGs x 512 threads = 4 chains x 64 WGs.
// WG (chain, wg) owns 32 permuted gate cols (8 h-units x 4 gates) for the
// chain's 8 batches.  No explicit barriers: all cross-WG handoffs are
// sentinel-polled data loads.
// ---------------------------------------------------------------------------
__global__ __launch_bounds__(512) void scan_kernel(
    const f16* __restrict__ eg,      // [1024][CH][64][32][8]
    const float* __restrict__ dg,    // [64][CH][64][32][8]
    const f16* __restrict__ Wenc,    // [2048][512] rows in permuted col order
    const f16* __restrict__ Wdih,    // [2048][512]
    const f16* __restrict__ Wdhh,    // [2048][512]
    const f16* __restrict__ T2l,     // [512][512]
    const f16* __restrict__ CT2l,    // [512][1024]
    const float* __restrict__ wpt,   // [512]
    f16* __restrict__ h_hist,        // [CH][1089][8][512] slot0 zero, rest sentinel
    f16* __restrict__ q_hist,        // [CH][65][8][512]  slot0 zero, rest sentinel
    f16* __restrict__ ctb,           // [64][CH][8][512]  sentinel-filled
    float* __restrict__ ppart,       // [64][CH][8][64]   sentinel-filled
    float* __restrict__ dout) {      // [2048][512]
    const int bid = blockIdx.x;
    const int chain = bid >> 6;
    const int wg = bid & 63;
    const int tid = threadIdx.x;

    f16* hc = h_hist + (size_t)chain * 1089 * 4096;
    f16* qc = q_hist + (size_t)chain * 65 * 4096;

    __shared__ __align__(16) f16  Ws[32 * 520];    // 33280 B encoder weights
    __shared__ __align__(16) f16  hst[8 * 520];    //  8320 B h[t] staging
    __shared__ __align__(16) f16  qst[8 * 520];    //  prev ht staging (decoder)
    __shared__ __align__(16) f16  yst[8 * 520];    //  yt staging (decoder)
    __shared__ __align__(16) f16  ctst[8 * 520];   //  ct staging (decoder)
    __shared__ float part[512];
    __shared__ float zbS[64];
    __shared__ float spart[64 * 9];
    __shared__ float scS[64];
    __shared__ float atwS[64];
    __shared__ float ptS[1];

    // stage encoder weight slice (32 rows x 512) into LDS, 520-f16 padded rows
    {
        int r = tid >> 4, seg = tid & 15;
        const float4* s4 = (const float4*)(Wenc + (size_t)(wg * 32 + r) * 512) + seg * 4;
        float4 a0 = s4[0], a1 = s4[1], a2 = s4[2], a3 = s4[3];
        float4* d4 = (float4*)(Ws + r * 520) + seg * 4;
        d4[0] = a0; d4[1] = a1; d4[2] = a2; d4[3] = a3;
    }
    __syncthreads();

    const int c  = (tid >> 3) & 31;   // gate col (local)
    const int bq = tid & 7;           // batch (local)
    const int kh = tid >> 8;          // k half
    const int sb = tid >> 6, sj = tid & 63;   // staging: batch, 16B chunk (full row!)
    const int au = tid & 7, ab = tid >> 3;    // activation: uu, bq (tid<64)
    float creg = 0.0f;                // cell state (tid<64)

    float egv = 0.0f;
    if (kh == 0)
        egv = (float)eg[(size_t)chain * 16384 + wg * 256 + c * 8 + bq];

    // ---------------- encoder: 1024 steps, ZERO barriers ----------------
    for (int t = 0; t < 1024; t++) {
        {   // poll-stage h[t] (8KB) -> LDS; chunk (sb,sj) produced by WG sj
            i32x4 v = poll16(hc + (size_t)t * 4096 + sb * 512 + sj * 8);
            *((i32x4*)(hst + sb * 520) + sj) = v;
        }
        float egn = 0.0f;
        if (kh == 0 && t < 1023)   // prefetch next step's gate (in flight thru dot)
            egn = (float)eg[((size_t)(t + 1) * 4 + chain) * 16384 + wg * 256 + c * 8 + bq];
        __syncthreads();
        {   // dot: col c, batch bq, k-half kh
            const f16* Wr = Ws + c * 520 + kh * 256;
            const f16* hr = hst + bq * 520 + kh * 256;
            float a0 = (kh == 0) ? egv : 0.0f;
#pragma unroll 8
            for (int k = 0; k < 256; k += 8) {
                V8 wv, xv;
                wv.f4 = *(const float4*)(Wr + k);
                xv.f4 = *(const float4*)(hr + k);
#pragma unroll
                for (int q = 0; q < 4; q++) a0 = dot2f(wv.p[q], xv.p[q], a0);
            }
            part[tid] = a0;
        }
        egv = egn;
        __syncthreads();
        if (tid < 64) {
            float gi = part[(au)      * 8 + ab] + part[256 + (au)      * 8 + ab];
            float gf = part[(8 + au)  * 8 + ab] + part[256 + (8 + au)  * 8 + ab];
            float gg = part[(16 + au) * 8 + ab] + part[256 + (16 + au) * 8 + ab];
            float go = part[(24 + au) * 8 + ab] + part[256 + (24 + au) * 8 + ab];
            float cc = sigf(gf) * creg + sigf(gi) * tanh_f(gg);
            float hh = sigf(go) * tanh_f(cc);
            creg = cc;
            // fire-and-forget: consumers poll the data itself
            st_wt_b16(hc + (size_t)(t + 1) * 4096 + ab * 512 + wg * 8 + au, (f16)hh);
        }
        // no barrier: next iteration's poll gates on h[t+1] arrival
    }

    // ---------------- decoder: 64 steps, ZERO barriers ----------------
    // pre-stage yst = hc[1024] (encoder final h; doubles as hsrc for t=0)
    {
        i32x4 v = poll16(hc + (size_t)1024 * 4096 + sb * 512 + sj * 8);
        *((i32x4*)(yst + sb * 520) + sj) = v;
    }

    for (int t = 0; t < 64; t++) {
        f16* ydst = hc + (size_t)(1025 + t) * 4096;       // yt slot

        // ---- stage A: gates = dg + Wih_h.ht + Whh.h; ht from qst, h from yst ----
        {   // poll-stage qc[t] (8KB) -> qst, full row coverage
            i32x4 v = poll16(qc + (size_t)t * 4096 + sb * 512 + sj * 8);
            *((i32x4*)(qst + sb * 520) + sj) = v;
        }
        __syncthreads();
        {
            float dgv = (kh == 0)
                ? dg[((size_t)t * 4 + chain) * 16384 + wg * 256 + c * 8 + bq] : 0.0f;
            const f16* W1 = Wdih + (size_t)(wg * 32 + c) * 512 + kh * 256;
            const f16* W2 = Wdhh + (size_t)(wg * 32 + c) * 512 + kh * 256;
            const f16* q0 = qst + bq * 520 + kh * 256;
            const f16* h0 = yst + bq * 520 + kh * 256;
            float a0 = dgv;
#pragma unroll 4
            for (int k = 0; k < 256; k += 8) {
                V8 w1, w2, x0, y0;
                w1.f4 = *(const float4*)(W1 + k);
                x0.f4 = *(const float4*)(q0 + k);
                w2.f4 = *(const float4*)(W2 + k);
                y0.f4 = *(const float4*)(h0 + k);
#pragma unroll
                for (int q = 0; q < 4; q++) {
                    a0 = dot2f(w1.p[q], x0.p[q], a0);
                    a0 = dot2f(w2.p[q], y0.p[q], a0);
                }
            }
            part[tid] = a0;
        }
        __syncthreads();
        if (tid < 64) {
            float gi = part[(au)      * 8 + ab] + part[256 + (au)      * 8 + ab];
            float gf = part[(8 + au)  * 8 + ab] + part[256 + (8 + au)  * 8 + ab];
            float gg = part[(16 + au) * 8 + ab] + part[256 + (16 + au) * 8 + ab];
            float go = part[(24 + au) * 8 + ab] + part[256 + (24 + au) * 8 + ab];
            float cc = sigf(gf) * creg + sigf(gi) * tanh_f(gg);
            float hh = sigf(go) * tanh_f(cc);
            creg = cc;
            st_wt_b16(ydst + ab * 512 + wg * 8 + au, (f16)hh);
        }

        // ---- stage B: poll-stage yt -> yst; z = tanh(yt @ W_ht2tan.T); pt partial ----
        {
            i32x4 v = poll16(ydst + sb * 512 + sj * 8);
            *((i32x4*)(yst + sb * 520) + sj) = v;
        }
        __syncthreads();
        {
            int kq = tid >> 6, zu = (tid >> 3) & 7, zq = tid & 7;
            const f16* Tr = T2l + (size_t)(wg * 8 + zu) * 512 + kq * 64;
            const f16* yr = yst + zq * 520 + kq * 64;
            float s = 0.0f;
#pragma unroll
            for (int k = 0; k < 64; k += 8) {
                V8 aa, bb;
                aa.f4 = *(const float4*)(Tr + k);
                bb.f4 = *(const float4*)(yr + k);
#pragma unroll
                for (int q = 0; q < 4; q++) s = dot2f(aa.p[q], bb.p[q], s);
            }
            part[tid] = s;
        }
        __syncthreads();
        if (tid < 64) {
            float z = 0.0f;
#pragma unroll
            for (int kq = 0; kq < 8; kq++) z += part[kq * 64 + tid];
            zbS[tid] = tanh_f(z);             // zbS[zu*8 + zq]
        }
        __syncthreads();
        if (tid < 8) {
            float pp = 0.0f;
#pragma unroll
            for (int u2 = 0; u2 < 8; u2++) pp += zbS[u2 * 8 + tid] * wpt[wg * 8 + u2];
            st_wt_f32(&ppart[(((size_t)t * 4 + chain) * 8 + tid) * 64 + wg], pp);
        }

        // ---- stage C: local attention (WG wg<8 owns chain-batch wg) ----
        if (wg < 8) {
            const int bb = wg;
            if (tid < 64) {
                const float* pa = ppart + (((size_t)t * 4 + chain) * 8 + bb) * 64 + tid;
                unsigned bits = ld_bypass_u32(pa);
                while (bits == 0xFFFFFFFFu) bits = ld_bypass_u32(pa);
                union { unsigned u; float f; } cv; cv.u = bits;
                float v = cv.f;
#pragma unroll
                for (int off = 32; off > 0; off >>= 1) v += __shfl_down(v, off);
                if (tid == 0) ptS[0] = v;
            }
            __syncthreads();
            float pt = sigf(ptS[0]);
            float center = 1024.0f * pt;
            int ci = (int)floorf(center);
            int left = max(0, ci - 32);
            int right = min(1024, ci + 32);
            int win = right - left;
            int p = tid >> 3, seg = tid & 7;
            if (p < win) {
                const f16* yr = yst + bb * 520 + seg * 64;
                const f16* er = hc + (size_t)(left + p + 1) * 4096 + bb * 512 + seg * 64;
                float s = 0.0f;
#pragma unroll
                for (int k = 0; k < 64; k += 8) {
                    V8 aa, bbv;
                    aa.f4  = *(const float4*)(yr + k);
                    bbv.f4 = *(const float4*)(er + k);
#pragma unroll
                    for (int q = 0; q < 4; q++) s = dot2f(aa.p[q], bbv.p[q], s);
                }
                spart[p * 9 + seg] = s;
            }
            __syncthreads();
            if (tid < 64) {
                float s = -1e30f;
                if (tid < win) {
                    s = 0.0f;
#pragma unroll
                    for (int x = 0; x < 8; x++) s += spart[tid * 9 + x];
                }
                scS[tid] = s;
            }
            __syncthreads();
            float mx = -1e30f;
            for (int q2 = 0; q2 < 64; q2++) mx = fmaxf(mx, scS[q2]);
            float sum = 0.0f;
            for (int q2 = 0; q2 < 64; q2++) sum += __expf(scS[q2] - mx);
            if (tid < 64) {
                float sp = (float)(left + tid) - center;
                float gs = __expf(-(sp * sp) * (1.0f / 512.0f));
                atwS[tid] = (tid < win) ? (__expf(scS[tid] - mx) / sum) * gs : 0.0f;
            }
            __syncthreads();
            {
                int j = tid;   // 0..511
                float a = 0.0f;
                const f16* ebase = hc + (size_t)(left + 1) * 4096 + bb * 512 + j;
                for (int p2 = 0; p2 < win; p2++)
                    a += atwS[p2] * (float)ebase[(size_t)p2 * 4096];
                st_wt_b16(ctb + ((((size_t)t * 4 + chain) * 8 + bb) * 512) + j, (f16)a);
            }
        }

        // ---- stage D: poll-stage ct -> ctst; ht_new = tanh([ct, yt] @ W_ct2ht.T) ----
        {
            i32x4 v = poll16(ctb + (((size_t)t * 4 + chain) * 8 + sb) * 512 + sj * 8);
            *((i32x4*)(ctst + sb * 520) + sj) = v;
        }
        __syncthreads();
        {
            int kq = tid >> 6, du = (tid >> 3) & 7, dq = tid & 7;
            const f16* Cr = CT2l + (size_t)(wg * 8 + du) * 1024 + kq * 128;
            const f16* xr = (kq < 4)
                ? (ctst + dq * 520 + kq * 128)
                : (yst + dq * 520 + (kq - 4) * 128);
            float s = 0.0f;
#pragma unroll 4
            for (int k = 0; k < 128; k += 8) {
                V8 aa, bb;
                aa.f4 = *(const float4*)(Cr + k);
                bb.f4 = *(const float4*)(xr + k);
#pragma unroll
                for (int q = 0; q < 4; q++) s = dot2f(aa.p[q], bb.p[q], s);
            }
            part[tid] = s;
        }
        __syncthreads();
        if (tid < 64) {
            float s = 0.0f;
#pragma unroll
            for (int kq = 0; kq < 8; kq++) s += part[kq * 64 + tid];
            float hv = tanh_f(s);
            int du = tid >> 3, dq = tid & 7;
            st_wt_b16(qc + (size_t)(t + 1) * 4096 + dq * 512 + wg * 8 + du, (f16)hv);
            dout[((size_t)t * 32 + chain * 8 + dq) * 512 + wg * 8 + du] = hv;
        }
        // no end barrier: stage A(t+1) polls qc[t+1]
    }
}

// ---------------------------------------------------------------------------
// Projection + fused exp-sum / target-logit extraction.
// ---------------------------------------------------------------------------
__global__ __launch_bounds__(256) void proj_lse(
    const float* __restrict__ A,      // dec_out [2048][512]
    const float* __restrict__ W,      // [32000][512]
    const int* __restrict__ target,   // [65][32]
    float* __restrict__ se, float* __restrict__ tl) {
    __shared__ float As[16][65];
    __shared__ float Bs[16][65];
    __shared__ float eb[64][17];
    const int tid = threadIdx.x;
    const int v0 = blockIdx.x * 64;
    const int r0 = blockIdx.y * 64;
    const int tx = tid & 15, ty = tid >> 4;
    const int lk = tid & 3,  lr = tid >> 2;
    const float* arow = A + (size_t)(r0 + lr) * 512 + lk * 4;
    const float* brow = W + (size_t)(v0 + lr) * 512 + lk * 4;
    float acc[4][4] = {};
    for (int k0 = 0; k0 < 512; k0 += 16) {
        float4 av = *(const float4*)(arow + k0);
        float4 bv = *(const float4*)(brow + k0);
        __syncthreads();
        As[lk * 4 + 0][lr] = av.x; As[lk * 4 + 1][lr] = av.y;
        As[lk * 4 + 2][lr] = av.z; As[lk * 4 + 3][lr] = av.w;
        Bs[lk * 4 + 0][lr] = bv.x; Bs[lk * 4 + 1][lr] = bv.y;
        Bs[lk * 4 + 2][lr] = bv.z; Bs[lk * 4 + 3][lr] = bv.w;
        __syncthreads();
#pragma unroll
        for (int k = 0; k < 16; k++) {
            float a4[4], b4[4];
#pragma unroll
            for (int i = 0; i < 4; i++) a4[i] = As[k][ty * 4 + i];
#pragma unroll
            for (int j = 0; j < 4; j++) b4[j] = Bs[k][tx * 4 + j];
#pragma unroll
            for (int i = 0; i < 4; i++)
#pragma unroll
                for (int j = 0; j < 4; j++) acc[i][j] = fmaf(a4[i], b4[j], acc[i][j]);
        }
    }
#pragma unroll
    for (int i = 0; i < 4; i++) {
        int rg = r0 + ty * 4 + i;
        int tg = target[32 + rg];
        float es = 0.0f;
#pragma unroll
        for (int j = 0; j < 4; j++) {
            int n = v0 + tx * 4 + j;
            float l = acc[i][j];
            if (n == tg) atomicAdd(&tl[rg], l);
            es += __expf(l);
        }
        eb[ty * 4 + i][tx] = es;
    }
    __syncthreads();
    if (tid < 64) {
        float s = 0.0f;
#pragma unroll
        for (int x = 0; x < 16; x++) s += eb[tid][x];
        atomicAdd(&se[r0 + tid], s);
    }
}

__global__ void finalize_out(const float* __restrict__ se, const float* __restrict__ tl,
                             const int* __restrict__ target, float* __restrict__ out) {
    int b = threadIdx.x;
    if (b >= 32) return;
    float s = 0.0f;
    for (int t = 0; t < 64; t++) {
        int r = t * 32 + b;
        int tg = target[(t + 1) * 32 + b];
        if (tg != 0) s += tl[r] - logf(se[r]);
    }
    out[b] = s;
}

// ---------------------------------------------------------------------------
extern "C" void kernel_launch(void* const* d_in, const int* in_sizes, int n_in,
                              void* d_out, int out_size, void* d_ws, size_t ws_size,
                              hipStream_t stream) {
    const int*   source   = (const int*)  d_in[0];
    const int*   target   = (const int*)  d_in[1];
    const float* src_emb  = (const float*)d_in[2];
    const float* tar_emb  = (const float*)d_in[3];
    const float* enc_Wih  = (const float*)d_in[4];
    const float* enc_Whh  = (const float*)d_in[5];
    const float* enc_b    = (const float*)d_in[6];
    const float* dec_Wih  = (const float*)d_in[7];
    const float* dec_Whh  = (const float*)d_in[8];
    const float* dec_b    = (const float*)d_in[9];
    const float* W_ht2tan = (const float*)d_in[10];
    const float* W_tan2pt = (const float*)d_in[11];
    const float* W_ct2ht  = (const float*)d_in[12];
    const float* W_final  = (const float*)d_in[13];
    float* out = (float*)d_out;

    char* ws = (char*)d_ws;
    size_t off = 0;
    auto alloc = [&](size_t bytes) -> char* {
        char* p = ws + off;
        off = (off + bytes + 255) & ~(size_t)255;
        return p;
    };
    f16*   h_hist = (f16*)  alloc((size_t)CH * 1089 * 4096 * 2);  // 35.7 MB
    f16*   q_hist = (f16*)  alloc((size_t)CH * 65 * 4096 * 2);
    f16*   ctb    = (f16*)  alloc((size_t)64 * CH * 8 * 512 * 2);
    float* ppart  = (float*)alloc((size_t)64 * CH * 8 * 64 * 4);
    float* se     = (float*)alloc((size_t)2048 * 4);
    float* tl     = (float*)alloc((size_t)2048 * 4);
    f16*   eg     = (f16*)  alloc((size_t)32768 * 2048 * 2);      // 128 MB
    float* dg     = (float*)alloc((size_t)2048 * 2048 * 4);       // 16 MB
    f16*   Wenc   = (f16*)  alloc((size_t)2048 * 512 * 2);
    f16*   Wdih   = (f16*)  alloc((size_t)2048 * 512 * 2);
    f16*   Wdhh   = (f16*)  alloc((size_t)2048 * 512 * 2);
    f16*   T2l    = (f16*)  alloc((size_t)512 * 512 * 2);
    f16*   CT2l   = (f16*)  alloc((size_t)512 * 1024 * 2);
    float* dout   = (float*)alloc((size_t)2048 * 512 * 4);

    fill_sentinel<<<2048, 256, 0, stream>>>((i32x4*)h_hist, (i32x4*)q_hist,
                                            (i32x4*)ctb, (i32x4*)ppart, se, tl);
    convert_weights<<<2048, 256, 0, stream>>>(enc_Whh, dec_Wih, dec_Whh, W_ht2tan, W_ct2ht,
                                              Wenc, Wdih, Wdhh, T2l, CT2l);
    gemm_gather<f16><<<dim3(32, 512), 256, 0, stream>>>(src_emb, source, enc_Wih, 512,
                                                        enc_b, eg);
    gemm_gather<float><<<dim3(32, 32), 256, 0, stream>>>(tar_emb, target, dec_Wih, 1024,
                                                         dec_b, dg);
    scan_kernel<<<CH * WPC, 512, 0, stream>>>(eg, dg, Wenc, Wdih, Wdhh, T2l, CT2l,
                                              W_tan2pt, h_hist, q_hist, ctb, ppart,
                                              dout);
    proj_lse<<<dim3(500, 32), 256, 0, stream>>>(dout, W_final, target, se, tl);
    finalize_out<<<1, 64, 0, stream>>>(se, tl, target, out);
}